// Round 4
// baseline (43.779 us; speedup 1.0000x reference)
//
#include <hip/hip_runtime.h>
#include <math.h>

#define NB 64
#define NK 40
#define TDIM 16
#define IMH 96
#define IMW 96
#define HW (IMH*IMW)
#define PLANES (NK+1)
#define PSTR 20                     // padded LDS row stride
#define PROWS 19
#define GPP (HW/4)                  // 2304 float4-groups per plane
#define NBLK 2048                   // 8 blocks/CU * 256 CUs: one even round
#define GPB ((NB*PLANES*GPP)/NBLK)  // 2952 groups per block, exact

typedef float f32x4 __attribute__((ext_vector_type(4)));

__global__ __launch_bounds__(256, 8) void TemplateImageDecoder_kernel(
    const float* __restrict__ poses,
    const float* __restrict__ presences,
    const float* __restrict__ templates,
    const float* __restrict__ bg_value,
    const float* __restrict__ temperature_logit,
    float* __restrict__ out)
{
    const int tid = threadIdx.x;
    const int bid = blockIdx.x;

    // temperature = softplus(temperature_logit + 0.5) + 1e-4 (uniform scalar)
    const float tl = temperature_logit[0] + 0.5f;
    const float sp = (tl > 0.0f) ? (tl + log1pf(expf(-tl))) : log1pf(expf(tl));
    const float invT = 1.0f / (sp + 1e-4f);

    // zero-padded sigmoid(template) in LDS; border cells stay 0 forever,
    // interior 16x16 is re-staged per plane segment.
    __shared__ float P[PROWS * PSTR];
    for (int i = tid; i < PROWS * PSTR; i += 256) P[i] = 0.0f;

    int s = bid * GPB;
    const int e = s + GPB;
    f32x4* __restrict__ outL_base = reinterpret_cast<f32x4*>(out);
    f32x4* __restrict__ outM_base = reinterpret_cast<f32x4*>(out + (size_t)NB * PLANES * HW);

    while (s < e) {
        const int plane = s / GPP;              // block-uniform
        const int o = s - plane * GPP;
        const int n = min(e - s, GPP - o);
        const int b = plane / PLANES;
        const int k = plane - b * PLANES;
        f32x4* __restrict__ oL = outL_base + (size_t)plane * GPP;
        f32x4* __restrict__ oM = outM_base + (size_t)plane * GPP;

        if (k == NK) {
            // background plane: constant fill
            const float bg  = 1.0f / (1.0f + expf(-bg_value[0]));
            const float bgl = bg * invT;
            const f32x4 vl = {bgl, bgl, bgl, bgl};
            const f32x4 vm = {bg,  bg,  bg,  bg};
            for (int g = o + tid; g < o + n; g += 256) {
                __builtin_nontemporal_store(vl, &oL[g]);
                __builtin_nontemporal_store(vm, &oM[g]);
            }
        } else {
            __syncthreads();   // previous segment's LDS reads complete
            {
                const float tv = templates[k * TDIM * TDIM + tid];
                const int y = tid >> 4, x = tid & 15;
                P[(y + 1) * PSTR + (x + 1)] = 1.0f / (1.0f + __expf(-tv));
            }
            const float* __restrict__ th = poses + ((size_t)b * NK + k) * 6;
            // ix = 8*(t00*gx + t01*gy + t02) + 7.5 ; fold *8 and +7.5
            const float ax = 8.0f * th[0], bx_ = 8.0f * th[1], cx = fmaf(8.0f, th[2], 7.5f);
            const float ay = 8.0f * th[3], by_ = 8.0f * th[4], cy = fmaf(8.0f, th[5], 7.5f);
            const float sx = ax * (2.0f / IMW);
            const float sy = ay * (2.0f / IMW);
            const float lp = logf(fmaxf(presences[b * NK + k], 1e-16f));
            __syncthreads();

            #pragma unroll 2
            for (int g = o + tid; g < o + n; g += 256) {
                const unsigned ug = (unsigned)g;
                const int h  = ug / (IMW / 4);
                const int w0 = (ug - h * (IMW / 4)) * 4;
                const float gy  = (2.0f * h + 1.0f) * (1.0f / IMH) - 1.0f;
                const float gx0 = (2.0f * w0 + 1.0f) * (1.0f / IMW) - 1.0f;
                const float ix0 = fmaf(ax, gx0, fmaf(bx_, gy, cx));
                const float iy0 = fmaf(ay, gx0, fmaf(by_, gy, cy));
                f32x4 rM, rL;
                #pragma unroll
                for (int j = 0; j < 4; ++j) {
                    float ix = fmaf((float)j, sx, ix0);
                    float iy = fmaf((float)j, sy, iy0);
                    ix = fminf(fmaxf(ix, -1.0f), 16.0f);
                    iy = fminf(fmaxf(iy, -1.0f), 16.0f);
                    const float x0f = floorf(ix), y0f = floorf(iy);
                    const float fx = ix - x0f,   fy = iy - y0f;
                    const int   x0 = (int)x0f,   y0 = (int)y0f;
                    const int base = (y0 + 1) * PSTR + (x0 + 1);
                    const float v00 = P[base],        v01 = P[base + 1];
                    const float v10 = P[base + PSTR], v11 = P[base + PSTR + 1];
                    const float wx0 = 1.0f - fx, wy0 = 1.0f - fy;
                    const float top = fmaf(fx, v01, wx0 * v00);
                    const float bot = fmaf(fx, v11, wx0 * v10);
                    const float acc = fmaf(fy, bot, wy0 * top);
                    rM[j] = acc;
                    rL[j] = fmaf(acc, invT, lp);
                }
                __builtin_nontemporal_store(rM, &oM[g]);
                __builtin_nontemporal_store(rL, &oL[g]);
            }
        }
        s += n;
    }
}

extern "C" void kernel_launch(void* const* d_in, const int* in_sizes, int n_in,
                              void* d_out, int out_size, void* d_ws, size_t ws_size,
                              hipStream_t stream) {
    const float* poses             = (const float*)d_in[0];
    const float* presences         = (const float*)d_in[1];
    const float* templates         = (const float*)d_in[2];
    const float* bg_value          = (const float*)d_in[3];
    const float* temperature_logit = (const float*)d_in[4];
    float* out = (float*)d_out;

    TemplateImageDecoder_kernel<<<dim3(NBLK), dim3(256), 0, stream>>>(
        poses, presences, templates, bg_value, temperature_logit, out);
}

// Round 5
// 37.157 us; speedup vs baseline: 1.1782x; 1.1782x over previous
//
#include <hip/hip_runtime.h>
#include <math.h>

#define NB 64
#define NK 40
#define TDIM 16
#define IMH 96
#define IMW 96
#define HW (IMH*IMW)
#define PLANES (NK+1)
#define PSTR 20                     // padded LDS row stride
#define PROWS 19
#define GPP (HW/4)                  // 2304 float4-groups per plane
#define NBLK 2048                   // 8 blocks/CU * 256 CUs: one even round
#define GPB ((NB*PLANES*GPP)/NBLK)  // 2952 groups per block, exact

typedef float f32x4 __attribute__((ext_vector_type(4)));

__global__ __launch_bounds__(256) void TemplateImageDecoder_kernel(
    const float* __restrict__ poses,
    const float* __restrict__ presences,
    const float* __restrict__ templates,
    const float* __restrict__ bg_value,
    const float* __restrict__ temperature_logit,
    float* __restrict__ out)
{
    const int tid = threadIdx.x;
    const int bid = blockIdx.x;

    // temperature = softplus(temperature_logit + 0.5) + 1e-4 (uniform scalar)
    const float tl = temperature_logit[0] + 0.5f;
    const float sp = (tl > 0.0f) ? (tl + log1pf(expf(-tl))) : log1pf(expf(tl));
    const float invT = 1.0f / (sp + 1e-4f);

    // zero-padded sigmoid(template) in LDS; border cells stay 0 forever,
    // interior 16x16 is re-staged per plane segment.
    __shared__ float P[PROWS * PSTR];
    for (int i = tid; i < PROWS * PSTR; i += 256) P[i] = 0.0f;

    int s = bid * GPB;
    const int e = s + GPB;
    f32x4* __restrict__ outL_base = reinterpret_cast<f32x4*>(out);
    f32x4* __restrict__ outM_base = reinterpret_cast<f32x4*>(out + (size_t)NB * PLANES * HW);

    while (s < e) {
        const int plane = s / GPP;              // block-uniform
        const int o = s - plane * GPP;
        const int n = min(e - s, GPP - o);
        const int b = plane / PLANES;
        const int k = plane - b * PLANES;
        f32x4* __restrict__ oL = outL_base + (size_t)plane * GPP;
        f32x4* __restrict__ oM = outM_base + (size_t)plane * GPP;

        if (k == NK) {
            // background plane: constant fill
            const float bg  = 1.0f / (1.0f + expf(-bg_value[0]));
            const float bgl = bg * invT;
            const f32x4 vl = {bgl, bgl, bgl, bgl};
            const f32x4 vm = {bg,  bg,  bg,  bg};
            for (int g = o + tid; g < o + n; g += 256) {
                oL[g] = vl;
                oM[g] = vm;
            }
        } else {
            __syncthreads();   // previous segment's LDS reads complete
            {
                const float tv = templates[k * TDIM * TDIM + tid];
                const int y = tid >> 4, x = tid & 15;
                P[(y + 1) * PSTR + (x + 1)] = 1.0f / (1.0f + __expf(-tv));
            }
            const float* __restrict__ th = poses + ((size_t)b * NK + k) * 6;
            // ix = 8*(t00*gx + t01*gy + t02) + 7.5 ; fold *8 and +7.5
            const float ax = 8.0f * th[0], bx_ = 8.0f * th[1], cx = fmaf(8.0f, th[2], 7.5f);
            const float ay = 8.0f * th[3], by_ = 8.0f * th[4], cy = fmaf(8.0f, th[5], 7.5f);
            const float sx = ax * (2.0f / IMW);
            const float sy = ay * (2.0f / IMW);
            const float lp = logf(fmaxf(presences[b * NK + k], 1e-16f));
            __syncthreads();

            #pragma unroll 2
            for (int g = o + tid; g < o + n; g += 256) {
                const unsigned ug = (unsigned)g;
                const int h  = ug / (IMW / 4);
                const int w0 = (ug - h * (IMW / 4)) * 4;
                const float gy  = (2.0f * h + 1.0f) * (1.0f / IMH) - 1.0f;
                const float gx0 = (2.0f * w0 + 1.0f) * (1.0f / IMW) - 1.0f;
                const float ix0 = fmaf(ax, gx0, fmaf(bx_, gy, cx));
                const float iy0 = fmaf(ay, gx0, fmaf(by_, gy, cy));
                f32x4 rM, rL;
                #pragma unroll
                for (int j = 0; j < 4; ++j) {
                    float ix = fmaf((float)j, sx, ix0);
                    float iy = fmaf((float)j, sy, iy0);
                    ix = fminf(fmaxf(ix, -1.0f), 16.0f);
                    iy = fminf(fmaxf(iy, -1.0f), 16.0f);
                    const float x0f = floorf(ix), y0f = floorf(iy);
                    const float fx = ix - x0f,   fy = iy - y0f;
                    const int   x0 = (int)x0f,   y0 = (int)y0f;
                    const int base = (y0 + 1) * PSTR + (x0 + 1);
                    const float v00 = P[base],        v01 = P[base + 1];
                    const float v10 = P[base + PSTR], v11 = P[base + PSTR + 1];
                    const float wx0 = 1.0f - fx, wy0 = 1.0f - fy;
                    const float top = fmaf(fx, v01, wx0 * v00);
                    const float bot = fmaf(fx, v11, wx0 * v10);
                    const float acc = fmaf(fy, bot, wy0 * top);
                    rM[j] = acc;
                    rL[j] = fmaf(acc, invT, lp);
                }
                oM[g] = rM;
                oL[g] = rL;
            }
        }
        s += n;
    }
}

extern "C" void kernel_launch(void* const* d_in, const int* in_sizes, int n_in,
                              void* d_out, int out_size, void* d_ws, size_t ws_size,
                              hipStream_t stream) {
    const float* poses             = (const float*)d_in[0];
    const float* presences         = (const float*)d_in[1];
    const float* templates         = (const float*)d_in[2];
    const float* bg_value          = (const float*)d_in[3];
    const float* temperature_logit = (const float*)d_in[4];
    float* out = (float*)d_out;

    TemplateImageDecoder_kernel<<<dim3(NBLK), dim3(256), 0, stream>>>(
        poses, presences, templates, bg_value, temperature_logit, out);
}

// Round 6
// 36.145 us; speedup vs baseline: 1.2112x; 1.0280x over previous
//
#include <hip/hip_runtime.h>
#include <math.h>

#define NB 64
#define NK 40
#define TDIM 16
#define IMH 96
#define IMW 96
#define HW (IMH*IMW)
#define PLANES (NK+1)
#define PSTR 20            // padded LDS row stride
#define PROWS 19
#define GPP (HW/4)         // 2304 float4-groups per plane
#define GPW (GPP/4)        // 576 groups per wave strip
#define IPW (GPW/64)       // 9 iterations per wave

typedef float f32x4 __attribute__((ext_vector_type(4)));

__global__ __launch_bounds__(256) void TemplateImageDecoder_kernel(
    const float* __restrict__ poses,
    const float* __restrict__ presences,
    const float* __restrict__ templates,
    const float* __restrict__ bg_value,
    const float* __restrict__ temperature_logit,
    float* __restrict__ out)
{
    const int tid  = threadIdx.x;
    const int bid  = blockIdx.x;
    const int b    = bid / PLANES;
    const int k    = bid - b * PLANES;
    const int wid  = tid >> 6;
    const int lane = tid & 63;

    // temperature = softplus(temperature_logit + 0.5) + 1e-4 (uniform scalar)
    const float tl = temperature_logit[0] + 0.5f;
    const float sp = (tl > 0.0f) ? (tl + log1pf(expf(-tl))) : log1pf(expf(tl));
    const float invT = 1.0f / (sp + 1e-4f);

    const size_t plane = (size_t)bid * GPP;   // bid == b*PLANES + k
    f32x4* __restrict__ oL = reinterpret_cast<f32x4*>(out) + plane;
    f32x4* __restrict__ oM = reinterpret_cast<f32x4*>(out) + (size_t)NB * PLANES * GPP + plane;

    if (k == NK) {
        // background plane: constant fill
        const float bg  = 1.0f / (1.0f + expf(-bg_value[0]));
        const float bgl = bg * invT;
        const f32x4 vl = {bgl, bgl, bgl, bgl};
        const f32x4 vm = {bg,  bg,  bg,  bg};
        for (int g = tid; g < GPP; g += 256) { oL[g] = vl; oM[g] = vm; }
        return;
    }

    // zero-padded sigmoid(template) in LDS: border cells are 0 so clamped
    // coordinates reproduce the reference's OOB masking exactly.
    __shared__ float P[PROWS * PSTR];
    for (int i = tid; i < PROWS * PSTR; i += 256) P[i] = 0.0f;
    __syncthreads();
    {
        const float tv = templates[k * TDIM * TDIM + tid];
        const int y = tid >> 4, x = tid & 15;
        P[(y + 1) * PSTR + (x + 1)] = 1.0f / (1.0f + __expf(-tv));
    }

    const float* __restrict__ th = poses + ((size_t)b * NK + k) * 6;
    // ix = 8*(t00*gx + t01*gy + t02) + 7.5 ; fold *8 and +7.5
    const float ax = 8.0f * th[0], bx_ = 8.0f * th[1], cx = fmaf(8.0f, th[2], 7.5f);
    const float ay = 8.0f * th[3], by_ = 8.0f * th[4], cy = fmaf(8.0f, th[5], 7.5f);
    const float sx = ax * (2.0f / IMW);
    const float sy = ay * (2.0f / IMW);
    const float lp = logf(fmaxf(presences[b * NK + k], 1e-16f));
    __syncthreads();

    // Each wave owns a contiguous 576-group strip; start phase rotated per
    // wave+block to break store-burst convoys across co-resident waves.
    const int gbase = wid * GPW + lane;
    const int rot   = ((wid + bid) & 3) * 2;   // 0,2,4,6

    auto body = [&](int it) {
        const int g  = gbase + it * 64;
        const unsigned ug = (unsigned)g;
        const int h  = ug / (IMW / 4);
        const int w0 = (ug - h * (IMW / 4)) * 4;
        const float gy  = (2.0f * h + 1.0f) * (1.0f / IMH) - 1.0f;
        const float gx0 = (2.0f * w0 + 1.0f) * (1.0f / IMW) - 1.0f;
        const float ix0 = fmaf(ax, gx0, fmaf(bx_, gy, cx));
        const float iy0 = fmaf(ay, gx0, fmaf(by_, gy, cy));
        f32x4 rM, rL;
        #pragma unroll
        for (int j = 0; j < 4; ++j) {
            float ix = fmaf((float)j, sx, ix0);
            float iy = fmaf((float)j, sy, iy0);
            ix = fminf(fmaxf(ix, -1.0f), 16.0f);
            iy = fminf(fmaxf(iy, -1.0f), 16.0f);
            const float x0f = floorf(ix), y0f = floorf(iy);
            const float fx = ix - x0f,   fy = iy - y0f;
            const int   x0 = (int)x0f,   y0 = (int)y0f;
            const int base = (y0 + 1) * PSTR + (x0 + 1);
            const float v00 = P[base],        v01 = P[base + 1];
            const float v10 = P[base + PSTR], v11 = P[base + PSTR + 1];
            const float wx0 = 1.0f - fx, wy0 = 1.0f - fy;
            const float top = fmaf(fx, v01, wx0 * v00);
            const float bot = fmaf(fx, v11, wx0 * v10);
            const float acc = fmaf(fy, bot, wy0 * top);
            rM[j] = acc;
            rL[j] = fmaf(acc, invT, lp);
        }
        oM[g] = rM;
        oL[g] = rL;
    };

    for (int it = rot; it < IPW; ++it) body(it);
    for (int it = 0;   it < rot; ++it) body(it);
}

extern "C" void kernel_launch(void* const* d_in, const int* in_sizes, int n_in,
                              void* d_out, int out_size, void* d_ws, size_t ws_size,
                              hipStream_t stream) {
    const float* poses             = (const float*)d_in[0];
    const float* presences         = (const float*)d_in[1];
    const float* templates         = (const float*)d_in[2];
    const float* bg_value          = (const float*)d_in[3];
    const float* temperature_logit = (const float*)d_in[4];
    float* out = (float*)d_out;

    TemplateImageDecoder_kernel<<<dim3(NB * PLANES), dim3(256), 0, stream>>>(
        poses, presences, templates, bg_value, temperature_logit, out);
}